// Round 7
// baseline (2816.493 us; speedup 1.0000x reference)
//
#include <hip/hip_runtime.h>
#include <hip/hip_bf16.h>
#include <hip/hip_fp16.h>
#include <cstdint>
#include <cstddef>

// B=128 T=96 D=256 H=256 C=8 M=64
// gates(n=4j+g) = zc[t,b,n] + h @ Uh[n]^T + t @ G[n]^T
//   Uh[n][256] = W_h[j] + W_xi[j]@Wfc           (k_fold)
//   G [n][512] = sum_d W_gd[n][d]*mem[cm][d]    (k_foldG)
//   zc[t*128+b][n] = bias2[n] + [z|zp]@Uz^T     (fp16, k_zc)
// scores[b][cm] = scoresZ[t,b,cm] + h @ SX[cm]^T
//   SX[cm][k]  = sum_d mask(c,d)*mem[cm][d]*lw2[d]*Wfc[d][k]   (k_foldSX)
//   scoresZ    = [z|zp]@Bz^T + bX  (k_sz, fp16, IN-PLACE over Zcat)
// k_main: 128 blocks = 8 groups(16 batch rows) x 16 N-slices; weights LDS-
// resident; 2 slot-store barriers/step (no RMW polling); h parity-buffered.

#define PLANE 24576   // 96*256

using bf16_t = __hip_bfloat16;
typedef __bf16 bf16x8 __attribute__((ext_vector_type(8)));
typedef float  f32x4  __attribute__((ext_vector_type(4)));

__device__ __forceinline__ float  b2f(bf16_t v){ return __bfloat162float(v); }
__device__ __forceinline__ bf16_t f2b(float v){ return __float2bfloat16(v); }
__device__ __forceinline__ float ldF(const void* p, size_t i, int f32){
  return f32 ? ((const float*)p)[i] : b2f(((const bf16_t*)p)[i]);
}
__device__ __forceinline__ bf16x8 ld_frag(const void* p){
  union { uint4 u; bf16x8 v; } c;
  c.u = *(const uint4*)p;
  return c.v;
}
__device__ __forceinline__ f32x4 mfma_bf16(bf16x8 a, bf16x8 b, f32x4 c){
  return __builtin_amdgcn_mfma_f32_16x16x32_bf16(a, b, c, 0, 0, 0);
}

// group barrier: per-block slot stores (separate cachelines) + load polling.
// arrive==true blocks store epoch to slot sidx; everyone polls nslots slots.
__device__ __forceinline__ void gbar(int* slots, int sidx, int nslots,
                                     int epoch, bool arrive){
  __syncthreads();
  if (arrive && threadIdx.x == 0){
    __threadfence();
    __hip_atomic_store(&slots[sidx*16], epoch, __ATOMIC_RELAXED,
                       __HIP_MEMORY_SCOPE_AGENT);
  }
  if (threadIdx.x < 64){
    const int sl = (threadIdx.x & (nslots-1))*16;
    while (__hip_atomic_load(&slots[sl], __ATOMIC_RELAXED,
                             __HIP_MEMORY_SCOPE_AGENT) < epoch)
      __builtin_amdgcn_s_sleep(1);
  }
  __syncthreads();
  __threadfence();
}

// ---------------- dtype detection ----------------
__global__ __launch_bounds__(64) void k_detect(
    const uint32_t* __restrict__ xu, const uint32_t* __restrict__ clu,
    int* __restrict__ flags)
{
  __shared__ int cnt[2];
  int t = threadIdx.x;
  if (t < 2) cnt[t] = 0;
  __syncthreads();
  uint32_t v = xu[2*PLANE + t];
  if (v == 0u || v == 0x3F800000u) atomicAdd(&cnt[0], 1);
  if (clu[2*t + 1] == 0u) atomicAdd(&cnt[1], 1);
  __syncthreads();
  if (t == 0){
    flags[0] = (cnt[0] >= 48) ? 1 : 0;
    flags[1] = (cnt[1] >= 60) ? 1 : 0;
  }
}

__global__ __launch_bounds__(1024) void k_zero(int* __restrict__ bar){
  bar[blockIdx.x*1024 + threadIdx.x] = 0;
}

// ---------------- canonicalize small tensors ----------------
__global__ __launch_bounds__(256) void k_canon(
    const void* __restrict__ Wfc, const void* __restrict__ Xmean,
    const void* __restrict__ bfc, const void* __restrict__ localw,
    const void* __restrict__ globalw, const void* __restrict__ gzw,
    const void* __restrict__ gzb, const void* __restrict__ gzpw,
    const void* __restrict__ gzpb, const int* __restrict__ flags,
    bf16_t* __restrict__ WfcC, bf16_t* __restrict__ XmC,
    bf16_t* __restrict__ bfcC, bf16_t* __restrict__ lwC,
    bf16_t* __restrict__ gwC, float* __restrict__ gzC)
{
  const int f32 = flags[0];
  int i = blockIdx.x*256 + threadIdx.x;
  if (i < 65536) WfcC[i] = f2b(ldF(Wfc, i, f32));
  if (i < 24576) XmC[i]  = f2b(ldF(Xmean, i, f32));
  if (i < 256)   bfcC[i] = f2b(ldF(bfc, i, f32));
  if (i < 768)   lwC[i]  = f2b(ldF(localw, i, f32));
  if (i < 8)     gwC[i]  = f2b(ldF(globalw, i, f32));
  if (i < 256){
    gzC[i]       = ldF(gzw,  i, f32);
    gzC[256 + i] = ldF(gzb,  i, f32);
    gzC[512 + i] = ldF(gzpw, i, f32);
    gzC[768 + i] = ldF(gzpb, i, f32);
  }
}

// ---------------- cluster-of-feature table ----------------
__global__ __launch_bounds__(256) void k_cof(
    const int* __restrict__ clusters, const int* __restrict__ flags,
    int* __restrict__ cofd)
{
  int d = threadIdx.x;
  int cv = flags[1] ? clusters[2*d] : clusters[d];
  cofd[d] = (cv - 1) & 7;
}

// ---------------- weight folding: Uh, Uz, bias2 ----------------
__global__ __launch_bounds__(256) void k_fold(
    const void* __restrict__ Wi, const void* __restrict__ Wf,
    const void* __restrict__ Wo, const void* __restrict__ Wc,
    const void* __restrict__ bi, const void* __restrict__ bfg,
    const void* __restrict__ bo, const void* __restrict__ bcg,
    const void* __restrict__ Wfc, const void* __restrict__ bfc,
    const int* __restrict__ flags,
    bf16_t* __restrict__ U, bf16_t* __restrict__ Uz, float* __restrict__ bias2)
{
  const int f32 = flags[0];
  int n = blockIdx.x; int g = n & 3; int j = n >> 2;
  const void* Wg = (g==0)?Wi:(g==1)?Wf:(g==2)?Wo:Wc;
  const void* bg = (g==0)?bi:(g==1)?bfg:(g==2)?bo:bcg;
  const size_t wb = (size_t)j*1280;
  int k = threadIdx.x;
  float acc = 0.f;
  for (int d=0; d<256; ++d)
    acc += ldF(Wg, wb+512+d, f32) * ldF(Wfc, (size_t)d*256+k, f32);
  U[(size_t)n*256 + k]        = f2b(acc + ldF(Wg, wb+1024+k, f32));
  Uz[(size_t)n*512 + k]       = f2b(ldF(Wg, wb+k, f32));
  Uz[(size_t)n*512 + 256 + k] = f2b(ldF(Wg, wb+256+k, f32));
  __shared__ float red[256];
  red[k] = ldF(Wg, wb+512+k, f32) * ldF(bfc, k, f32);
  __syncthreads();
  for (int s=128; s>0; s>>=1){ if (k<s) red[k]+=red[k+s]; __syncthreads(); }
  if (k==0) bias2[n] = red[0] + ldF(bg, j, f32);
}

// ---------------- G[n][cm] = sum_d W_gd[n][d] * mem[cm][d] ----------------
__global__ __launch_bounds__(256) void k_foldG(
    const void* __restrict__ Wi, const void* __restrict__ Wf,
    const void* __restrict__ Wo, const void* __restrict__ Wc,
    const void* __restrict__ memory, const int* __restrict__ flags,
    bf16_t* __restrict__ G)
{
  const int f32 = flags[0];
  __shared__ float wrow[4][256];
  int j = blockIdx.x; int tid = threadIdx.x;
  const void* Wg[4] = {Wi,Wf,Wo,Wc};
  for (int g=0; g<4; ++g)
    wrow[g][tid] = ldF(Wg[g], (size_t)j*1280 + 768 + tid, f32);
  __syncthreads();
  for (int half=0; half<2; ++half){
    int cm = half*256 + tid;
    float a0=0,a1=0,a2=0,a3=0;
    for (int d=0; d<256; ++d){
      float mv = ldF(memory, (size_t)cm*256 + d, f32);
      a0 += wrow[0][d]*mv; a1 += wrow[1][d]*mv;
      a2 += wrow[2][d]*mv; a3 += wrow[3][d]*mv;
    }
    G[(size_t)(4*j+0)*512 + cm] = f2b(a0);
    G[(size_t)(4*j+1)*512 + cm] = f2b(a1);
    G[(size_t)(4*j+2)*512 + cm] = f2b(a2);
    G[(size_t)(4*j+3)*512 + cm] = f2b(a3);
  }
}

// ---------------- SX / Bz / bX folds ----------------
__global__ __launch_bounds__(256) void k_foldSX(
    const void* __restrict__ memory, const int* __restrict__ flags,
    const int* __restrict__ cofd, const bf16_t* __restrict__ lwC,
    const bf16_t* __restrict__ WfcC, const bf16_t* __restrict__ bfcC,
    bf16_t* __restrict__ SX, bf16_t* __restrict__ Bz, float* __restrict__ bX)
{
  const int f32 = flags[0];
  int cm = blockIdx.x, c = cm >> 6;
  int tid = threadIdx.x;
  __shared__ float wd[256];
  __shared__ float red[256];
  float mv = ldF(memory, (size_t)cm*256 + tid, f32);
  bool msk = (cofd[tid] == c);
  float w2 = msk ? mv * b2f(lwC[512+tid]) : 0.f;
  wd[tid] = w2;
  Bz[(size_t)cm*512 + tid]       = f2b(msk ? mv*b2f(lwC[tid])     : 0.f);
  Bz[(size_t)cm*512 + 256 + tid] = f2b(msk ? mv*b2f(lwC[256+tid]) : 0.f);
  red[tid] = w2 * b2f(bfcC[tid]);
  __syncthreads();
  float acc = 0.f;
  for (int d=0; d<256; ++d) acc += wd[d] * b2f(WfcC[(size_t)d*256 + tid]);
  SX[(size_t)cm*256 + tid] = f2b(acc);
  __syncthreads();
  for (int s=128; s>0; s>>=1){ if (tid<s) red[tid]+=red[tid+s]; __syncthreads(); }
  if (tid==0) bX[cm] = red[0];
}

// ---------------- z / zp -> Zcat, t-major rows (t*128+b) ----------------
__global__ __launch_bounds__(256) void k_zzp(
    const void* __restrict__ x, const bf16_t* __restrict__ XmC,
    const float* __restrict__ gzC, const int* __restrict__ flags,
    bf16_t* __restrict__ Zcat)
{
  const int f32 = flags[0];
  int r = blockIdx.x;             // r = t*128 + b
  int t = r >> 7, b = r & 127, d = threadIdx.x;
  size_t base = (size_t)b*6*PLANE + (size_t)t*256 + d;
  float xt = ldF(x, base          , f32);
  float xl = ldF(x, base +   PLANE, f32);
  float mk = ldF(x, base + 2*PLANE, f32);
  float de = ldF(x, base + 3*PLANE, f32);
  float xlb= ldF(x, base + 4*PLANE, f32);
  float deb= ldF(x, base + 5*PLANE, f32);
  float mean = b2f(XmC[t*256+d]);
  float dz  = expf(-fmaxf(0.f, de *gzC[d]     + gzC[256+d]));
  float dzp = expf(-fmaxf(0.f, deb*gzC[512+d] + gzC[768+d]));
  float z  = mk*xt + (1.f-mk)*(dz *xl  + (1.f-dz )*mean);
  float zp = mk*xt + (1.f-mk)*(dzp*xlb + (1.f-dzp)*mean);
  Zcat[(size_t)r*512 + d]       = f2b(z);
  Zcat[(size_t)r*512 + 256 + d] = f2b(zp);
}

// ---------------- zc GEMM: zc[m][n] = bias2[n] + Zcat[m]@Uz^T (fp16) --------
__global__ __launch_bounds__(256) void k_zc(
    const bf16_t* __restrict__ Zcat, const bf16_t* __restrict__ Uz,
    const float* __restrict__ bias2, __half* __restrict__ zc)
{
  const int tid = threadIdx.x;
  const int w = tid>>6, l = tid&63, q=l>>4, cl=l&15;
  const int mq = w&1, nq = w>>1;
  const int m0 = blockIdx.x*128, n0 = blockIdx.y*128;
  f32x4 acc[4][4];
#pragma unroll
  for (int a=0;a<4;++a)
#pragma unroll
    for (int b2=0;b2<4;++b2) acc[a][b2] = (f32x4){0.f,0.f,0.f,0.f};
  for (int ks=0; ks<16; ++ks){
    bf16x8 av[4], bv[4];
#pragma unroll
    for (int mi=0;mi<4;++mi)
      av[mi] = ld_frag(&Zcat[(size_t)(m0+mq*64+mi*16+cl)*512 + ks*32 + q*8]);
#pragma unroll
    for (int ni=0;ni<4;++ni)
      bv[ni] = ld_frag(&Uz[(size_t)(n0+nq*64+ni*16+cl)*512 + ks*32 + q*8]);
#pragma unroll
    for (int mi=0;mi<4;++mi)
#pragma unroll
      for (int ni=0;ni<4;++ni)
        acc[mi][ni] = mfma_bf16(av[mi], bv[ni], acc[mi][ni]);
  }
#pragma unroll
  for (int mi=0;mi<4;++mi)
#pragma unroll
    for (int ni=0;ni<4;++ni)
#pragma unroll
      for (int rr=0;rr<4;++rr){
        int m = m0 + mq*64 + mi*16 + q*4 + rr;
        int n = n0 + nq*64 + ni*16 + cl;
        zc[(size_t)m*1024 + n] = __float2half(acc[mi][ni][rr] + bias2[n]);
      }
}

// ---- scoresZ = Zcat@Bz^T + bX, fp16 written IN-PLACE over Zcat rows --------
// block owns 64 full rows: stage A first, then chunked-B GEMM, overwrite safe.
__global__ __launch_bounds__(256) void k_sz(
    bf16_t* __restrict__ Zcat, const bf16_t* __restrict__ Bz,
    const float* __restrict__ bX)
{
  __shared__ bf16_t As[64][520];
  __shared__ bf16_t Bs[64][520];
  const int tid = threadIdx.x;
  const int W = tid>>6, l = tid&63, q=l>>4, cl=l&15;
  const int m0 = blockIdx.x*64;
  for (int i=tid; i<64*64; i+=256){ int r=i>>6, c8=(i&63)*8;
    *(uint4*)(&As[r][c8]) = *(const uint4*)(Zcat + (size_t)(m0+r)*512 + c8); }
  __syncthreads();
  for (int nc=0; nc<8; ++nc){
    for (int i=tid; i<64*64; i+=256){ int r=i>>6, c8=(i&63)*8;
      *(uint4*)(&Bs[r][c8]) = *(const uint4*)(Bz + (size_t)(nc*64+r)*512 + c8); }
    __syncthreads();
    const float bXv = bX[nc*64 + W*16 + cl];
    f32x4 acc[4];
#pragma unroll
    for (int mi=0;mi<4;++mi) acc[mi] = (f32x4){bXv,bXv,bXv,bXv};
    for (int ks=0; ks<16; ++ks){
      bf16x8 b = ld_frag(&Bs[W*16+cl][ks*32 + q*8]);
#pragma unroll
      for (int mi=0;mi<4;++mi){
        bf16x8 a = ld_frag(&As[mi*16+cl][ks*32 + q*8]);
        acc[mi] = mfma_bf16(a, b, acc[mi]);
      }
    }
#pragma unroll
    for (int mi=0;mi<4;++mi)
#pragma unroll
      for (int rr=0;rr<4;++rr)
        ((__half*)Zcat)[(size_t)(m0+mi*16+q*4+rr)*512 + nc*64 + W*16 + cl] =
          __float2half(acc[mi][rr]);
    __syncthreads();
  }
}

// ---------------- k_main: 128 blocks (8 groups x 16 slices) x 256 thr -------
__global__ __launch_bounds__(256) void k_main(
    const int* __restrict__ flags,
    const bf16_t* __restrict__ WfcC, const bf16_t* __restrict__ bfcC,
    const bf16_t* __restrict__ gwC,
    const bf16_t* __restrict__ U, const bf16_t* __restrict__ G,
    const bf16_t* __restrict__ SX, const __half* __restrict__ zc,
    const __half* __restrict__ ZS,
    bf16_t* __restrict__ hX, bf16_t* __restrict__ tX,
    int* __restrict__ bar, void* __restrict__ outv)
{
  __shared__ bf16_t Us[64][264];    // Uh slice (gate cols n0..n0+63)
  __shared__ bf16_t Gs[64][520];    // G slice
  __shared__ bf16_t WfcS[16][264];  // x_i cols s*16..
  __shared__ bf16_t SXs[64][264];   // score weights (cluster blocks)
  __shared__ float  scF[16][68];    // raw scores for softmax

  const int tid = threadIdx.x;
  const int W = tid>>6, l = tid&63, q = l>>4, cl = l&15;
  const int g = blockIdx.x & 7, s = blockIdx.x >> 3;
  const int r0 = g*16, n0 = s*64;
  const int f32 = flags[0];
  const bool isClu = (s < 8);
  int* barA = bar + g*1024;
  int* barB = barA + 256;

  for (int i=tid; i<64*32; i+=256){ int r=i>>5, c8=(i&31)*8;
    *(uint4*)(&Us[r][c8]) = *(const uint4*)(U + (size_t)(n0+r)*256 + c8); }
  for (int i=tid; i<64*64; i+=256){ int r=i>>6, c8=(i&63)*8;
    *(uint4*)(&Gs[r][c8]) = *(const uint4*)(G + (size_t)(n0+r)*512 + c8); }
  for (int i=tid; i<16*32; i+=256){ int r=i>>5, c8=(i&31)*8;
    *(uint4*)(&WfcS[r][c8]) = *(const uint4*)(WfcC + (size_t)(s*16+r)*256 + c8); }
  if (isClu)
    for (int i=tid; i<64*32; i+=256){ int r=i>>5, c8=(i&31)*8;
      *(uint4*)(&SXs[r][c8]) = *(const uint4*)(SX + (size_t)(s*64+r)*256 + c8); }
  const float gw_c = isClu ? b2f(gwC[s]) : 0.f;
  const float bfcv = b2f(bfcC[s*16 + cl]);
  float creg[4] = {0.f,0.f,0.f,0.f};
  bf16x8 hf[8];
  __syncthreads();

  for (int t=0; t<=96; ++t){
    // -- h fragments (VGPR-cached A for x_i / h-GEMM / scores)
    if (t == 0){
      union{uint4 u; bf16x8 v;} zz; zz.u = (uint4){0,0,0,0};
#pragma unroll
      for (int ks=0; ks<8; ++ks) hf[ks] = zz.v;
    } else {
      gbar(barA, s, 16, t, true);
      const bf16_t* hp = hX + (size_t)((t-1)&1)*128*256;
#pragma unroll
      for (int ks=0; ks<8; ++ks)
        hf[ks] = ld_frag(hp + (size_t)(r0+cl)*256 + ks*32 + q*8);
    }
    // -- x_i out slice (wave 0)
    if (W == 0 && t > 0){
      f32x4 xa = {0,0,0,0};
#pragma unroll
      for (int ks=0; ks<8; ++ks)
        xa = mfma_bf16(hf[ks], ld_frag(&WfcS[cl][ks*32 + q*8]), xa);
#pragma unroll
      for (int rr=0; rr<4; ++rr){
        float v = xa[rr] + bfcv;
        size_t ob = ((size_t)(r0+q*4+rr)*96 + (t-1))*256 + s*16 + cl;
        if (f32) ((float*)outv)[ob] = v; else ((bf16_t*)outv)[ob] = f2b(v);
      }
    }
    if (t == 96) break;
    // -- gates: zc init + h-part
    f32x4 acc;
#pragma unroll
    for (int rr=0; rr<4; ++rr)
      acc[rr] = __half2float(zc[((size_t)t*128 + r0 + q*4+rr)*1024 + n0 + W*16 + cl]);
#pragma unroll
    for (int ks=0; ks<8; ++ks)
      acc = mfma_bf16(hf[ks], ld_frag(&Us[W*16+cl][ks*32 + q*8]), acc);
    // -- cluster scores + softmax -> tX
    if (isClu){
      f32x4 sa;
#pragma unroll
      for (int rr=0; rr<4; ++rr)
        sa[rr] = __half2float(ZS[((size_t)t*128 + r0 + q*4+rr)*512 + s*64 + W*16 + cl]);
#pragma unroll
      for (int ks=0; ks<8; ++ks)
        sa = mfma_bf16(hf[ks], ld_frag(&SXs[W*16+cl][ks*32 + q*8]), sa);
#pragma unroll
      for (int rr=0; rr<4; ++rr) scF[q*4+rr][W*16+cl] = sa[rr];
      __syncthreads();
#pragma unroll
      for (int r=W*4; r<W*4+4; ++r){   // wave W -> rows W*4..W*4+3
        float v = scF[r][l];
        float mx = v;
        mx = fmaxf(mx, __shfl_xor(mx,1));
        mx = fmaxf(mx, __shfl_xor(mx,2));
        mx = fmaxf(mx, __shfl_xor(mx,4));
        mx = fmaxf(mx, __shfl_xor(mx,8));
        mx = fmaxf(mx, __shfl_xor(mx,16));
        mx = fmaxf(mx, __shfl_xor(mx,32));
        float e = expf(v - mx);
        float sm = e;
        sm += __shfl_xor(sm,1); sm += __shfl_xor(sm,2);
        sm += __shfl_xor(sm,4); sm += __shfl_xor(sm,8);
        sm += __shfl_xor(sm,16); sm += __shfl_xor(sm,32);
        tX[(size_t)(r0+r)*512 + s*64 + l] = f2b(e * gw_c / sm);
      }
    }
    gbar(barB, s, 8, t+1, isClu);
    // -- gates gd-part: A-frags from tX (L1-shared across waves), B=Gs
#pragma unroll
    for (int ks=0; ks<16; ++ks){
      bf16x8 a = ld_frag(tX + (size_t)(r0+cl)*512 + ks*32 + q*8);
      acc = mfma_bf16(a, ld_frag(&Gs[W*16+cl][ks*32 + q*8]), acc);
    }
    // -- LSTM update (lane quad = i,f,o,c of one j)
    const int base = l & ~3;
    bf16_t* hw = hX + (size_t)(t&1)*128*256;
#pragma unroll
    for (int rr=0; rr<4; ++rr){
      float p = acc[rr];
      float pi = __shfl(p, base+0);
      float pf = __shfl(p, base+1);
      float po = __shfl(p, base+2);
      float pc = __shfl(p, base+3);
      float iv = 1.f/(1.f+expf(-pi));
      float fv = 1.f/(1.f+expf(-pf));
      float ov = 1.f/(1.f+expf(-po));
      float cv = tanhf(pc);
      float cn = fv*creg[rr] + iv*cv;
      creg[rr] = cn;
      float hv = ov * tanhf(cn);
      if ((l&3)==0)
        hw[(size_t)(r0+q*4+rr)*256 + s*16 + W*4 + (cl>>2)] = f2b(hv);
    }
  }
}

extern "C" void kernel_launch(void* const* d_in, const int* in_sizes, int n_in,
                              void* d_out, int out_size, void* d_ws, size_t ws_size,
                              hipStream_t stream)
{
  const void* x       = d_in[0];
  const void* Xmean   = d_in[1];
  const int*  clusters= (const int*)d_in[2];
  const void* Wi  = d_in[3];
  const void* bi  = d_in[4];
  const void* Wf  = d_in[5];
  const void* bfp = d_in[6];
  const void* Wo  = d_in[7];
  const void* bo  = d_in[8];
  const void* Wc  = d_in[9];
  const void* bcp = d_in[10];
  const void* Wfc = d_in[11];
  const void* bfc = d_in[12];
  const void* gzw = d_in[13];
  const void* gzb = d_in[14];
  const void* gzpw= d_in[15];
  const void* gzpb= d_in[16];
  const void* memory = d_in[17];
  const void* localw = d_in[18];
  const void* globalw= d_in[19];
  (void)in_sizes; (void)n_in; (void)out_size; (void)ws_size;

  char* ws = (char*)d_ws;
  size_t off = 0;
  auto take = [&](size_t bytes)->char*{
    char* p = ws + off; off = (off + bytes + 255) & ~(size_t)255; return p; };
  int*    flags  = (int*)   take(16);
  int*    bar    = (int*)   take(8192*4);                 // 32 KB
  bf16_t* U      = (bf16_t*)take((size_t)1024*256*2);     // 0.5 MB
  bf16_t* Uz     = (bf16_t*)take((size_t)1024*512*2);     // 1 MB
  bf16_t* G      = (bf16_t*)take((size_t)1024*512*2);     // 1 MB
  bf16_t* SX     = (bf16_t*)take((size_t)512*256*2);      // 256 KB
  bf16_t* Bz     = (bf16_t*)take((size_t)512*512*2);      // 512 KB
  float*  bX     = (float*) take(512*4);
  bf16_t* WfcC   = (bf16_t*)take((size_t)65536*2);
  bf16_t* XmC    = (bf16_t*)take((size_t)24576*2);
  bf16_t* bfcC   = (bf16_t*)take(256*2);
  bf16_t* lwC    = (bf16_t*)take(768*2);
  bf16_t* gwC    = (bf16_t*)take(8*2);
  float*  gzC    = (float*) take(1024*4);
  float*  bias2  = (float*) take(1024*4);
  int*    cofd   = (int*)   take(256*4);
  bf16_t* hXb    = (bf16_t*)take((size_t)2*128*256*2);    // parity-buffered h
  bf16_t* tXb    = (bf16_t*)take((size_t)128*512*2);
  bf16_t* Zcat   = (bf16_t*)take((size_t)12288*512*2);    // 12.6 MB (-> scoresZ)
  __half* zc     = (__half*)take((size_t)12288*1024*2);   // 25.2 MB
  // total ~41.5 MB (same footprint as round 6, which fit)

  k_detect<<<1,    64,  0,stream>>>((const uint32_t*)x, (const uint32_t*)clusters, flags);
  k_zero  <<<8,    1024,0,stream>>>(bar);
  k_canon <<<256,  256, 0,stream>>>(Wfc, Xmean, bfc, localw, globalw,
                                    gzw, gzb, gzpw, gzpb, flags,
                                    WfcC, XmC, bfcC, lwC, gwC, gzC);
  k_cof   <<<1,    256, 0,stream>>>(clusters, flags, cofd);
  k_fold  <<<1024, 256, 0,stream>>>(Wi,Wf,Wo,Wc, bi,bfp,bo,bcp, Wfc,bfc, flags,
                                    U, Uz, bias2);
  k_foldG <<<256,  256, 0,stream>>>(Wi,Wf,Wo,Wc, memory, flags, G);
  k_foldSX<<<512,  256, 0,stream>>>(memory, flags, cofd, lwC, WfcC, bfcC,
                                    SX, Bz, bX);
  k_zzp   <<<12288,256, 0,stream>>>(x, XmC, gzC, flags, Zcat);
  k_zc    <<<dim3(96,8),256,0,stream>>>(Zcat, Uz, bias2, zc);
  k_sz    <<<192,  256, 0,stream>>>(Zcat, Bz, bX);
  k_main  <<<128,  256, 0,stream>>>(flags, WfcC, bfcC, gwC, U, G, SX, zc,
                                    (const __half*)Zcat, hXb, tXb, bar, d_out);
}